// Round 9
// baseline (447.370 us; speedup 1.0000x reference)
//
#include <hip/hip_runtime.h>
#include <hip/hip_bf16.h>
#include <cstdint>

// Problem constants
#define BB 4
#define CC 512
#define CQK 64
#define HH 129
#define WW 129
#define HS 65
#define WSZ 65
#define NN 4225            // HS*WSZ
#define NP 4352            // padded N (34*128)
#define KPV 4288           // 67 K-tiles of 64; P cols 4288.. are zero
#define OUTSZ 34080768     // BB*CC*HH*WW
#define ESZ 17850625       // NN*NN
#define PLANE 16641        // 129*129

typedef unsigned short u16;
typedef __attribute__((ext_vector_type(8))) __bf16 bfrag;
typedef __attribute__((ext_vector_type(4))) float f4v;
typedef __attribute__((ext_vector_type(16))) float f16v;

__device__ inline u16 f2bf(float f) {
    union { float f; unsigned int u; } v; v.f = f;
    unsigned int u = v.u;
    return (u16)((u + 0x7FFFu + ((u >> 16) & 1u)) >> 16);
}
__device__ inline float bf2f(u16 v) {
    union { unsigned u; float f; } x; x.u = (unsigned)v << 16; return x.f;
}

// async global->LDS, 16 bytes per lane; lds dest must be wave-uniform base
__device__ __forceinline__ void gload16(const u16* g, u16* l) {
    __builtin_amdgcn_global_load_lds(
        (const __attribute__((address_space(1))) void*)g,
        (__attribute__((address_space(3))) void*)l, 16, 0, 0);
}

// ---------------- K0: merged setup — cast weights (blocks 0..1279) + subsample-T (rest)
__global__ __launch_bounds__(256) void setup_k(const float* __restrict__ Wq,
                                               const float* __restrict__ Wk,
                                               const float* __restrict__ Wv,
                                               const float* __restrict__ x,
                                               u16* __restrict__ Wc,
                                               u16* __restrict__ XsT) {
    __shared__ u16 tile[64][65];
    if (blockIdx.x < 1280) {
        int idx = blockIdx.x * 256 + threadIdx.x;
        int o = idx >> 9, c = idx & 511;
        float v = (o < 64) ? Wq[o * 512 + c] : (o < 128) ? Wk[(o - 64) * 512 + c] : Wv[(o - 128) * 512 + c];
        Wc[idx] = f2bf(v);
        return;
    }
    int bid = blockIdx.x - 1280;
    int nt = bid % 68;
    int ct = (bid / 68) & 7;
    int b = bid / 544;
    int t = threadIdx.x;
#pragma unroll
    for (int l = 0; l < 16; ++l) {
        int e = t + l * 256;
        int ci = e >> 6, nj = e & 63;
        int n = nt * 64 + nj;
        int nc = n < (NN - 1) ? n : (NN - 1);
        int i = nc / 65, j = nc % 65;
        int c = ct * 64 + ci;
        float v = x[(((size_t)b * CC + c) * HH + 2 * i) * WW + 2 * j];
        tile[ci][nj] = f2bf(v);
    }
    __syncthreads();
#pragma unroll
    for (int l = 0; l < 16; ++l) {
        int e = t + l * 256;
        int nj = e >> 6, ci = e & 63;
        XsT[((size_t)b * NP + nt * 64 + nj) * 512 + ct * 64 + ci] = tile[ci][nj];
    }
}

// ---------------- QKV NT GEMM (m97 structure)
// A=Wc[640][512], B=XsT[b], out -> qkT[n][o] (o<128) / V[o-128][n], +bias, bf16
// flat grid 680 = 8 XCD slices x (17 n x 5 m, m fastest for B-panel L2 reuse)
__global__ __launch_bounds__(256) void gemm_qkv(const u16* __restrict__ Wc,
                                                const u16* __restrict__ XsT,
                                                u16* __restrict__ qkT, u16* __restrict__ Vout,
                                                const float* __restrict__ bq,
                                                const float* __restrict__ bk,
                                                const float* __restrict__ bv) {
    __shared__ __align__(16) u16 S[16384];
    u16* As = S;
    u16* Bs = S + 8192;

    unsigned flat = blockIdx.x;
    unsigned s = flat & 7u;
    unsigned k = flat >> 3;
    unsigned m = k % 5u;
    unsigned nl = k / 5u;
    const int z = (int)(s >> 1);
    const size_t m0 = (size_t)m * 128;
    const size_t n0 = ((size_t)(s & 1u) * 17u + nl) * 128;

    const u16* Ab = Wc + m0 * 512;
    const u16* Bb = XsT + (size_t)z * NP * 512 + n0 * 512;

    const int tid = threadIdx.x;
    const int lane = tid & 63, w = tid >> 6;
    const int wr = w >> 1, wc = w & 1;
    const int frow = lane & 15, fk = (lane >> 4) * 8;

    f4v acc[4][4];
#pragma unroll
    for (int i = 0; i < 4; ++i)
#pragma unroll
        for (int j = 0; j < 4; ++j) acc[i][j] = (f4v){0.f, 0.f, 0.f, 0.f};

    for (int kt = 0; kt < 512; kt += 64) {
        if (kt) __syncthreads();
#pragma unroll
        for (int it = 0; it < 4; ++it) {
            int cb = (it * 4 + w) * 64;
            int chunk = cb + lane;
            int r = chunk >> 3;
            int kc = (chunk & 7) << 3;
            gload16(Ab + (size_t)r * 512 + kt + kc, &As[cb * 8]);
            gload16(Bb + (size_t)r * 512 + kt + kc, &Bs[cb * 8]);
        }
        __syncthreads();
#pragma unroll
        for (int ks = 0; ks < 2; ++ks) {
            bfrag af[4], bf[4];
#pragma unroll
            for (int i = 0; i < 4; ++i)
                af[i] = *(const bfrag*)&As[(wr * 64 + i * 16 + frow) * 64 + ks * 32 + fk];
#pragma unroll
            for (int j = 0; j < 4; ++j)
                bf[j] = *(const bfrag*)&Bs[(wc * 64 + j * 16 + frow) * 64 + ks * 32 + fk];
#pragma unroll
            for (int i = 0; i < 4; ++i)
#pragma unroll
                for (int j = 0; j < 4; ++j)
                    acc[i][j] = __builtin_amdgcn_mfma_f32_16x16x32_bf16(af[i], bf[j], acc[i][j], 0, 0, 0);
        }
    }

    const int rbase = (lane >> 4) * 4, cbase = lane & 15;
    u16* out1b = qkT + (size_t)z * NP * 128;
    u16* out2b = Vout + (size_t)z * 512 * NP;
#pragma unroll
    for (int i = 0; i < 4; ++i)
#pragma unroll
        for (int j = 0; j < 4; ++j) {
            size_t row0 = m0 + wr * 64 + i * 16 + rbase;
            size_t col = n0 + wc * 64 + j * 16 + cbase;
#pragma unroll
            for (int r = 0; r < 4; ++r) {
                int o = (int)(row0 + r);
                float bias = (o < 64) ? bq[o] : (o < 128) ? bk[o - 64] : bv[o - 128];
                u16 bb = f2bf(acc[i][j][r] + bias);
                if (o < 128) out1b[col * 128 + o] = bb;
                else out2b[(size_t)(o - 128) * NP + col] = bb;
            }
        }
}

// ---------------- energy GEMM: 32x32x16 MFMA, XOR-swizzled LDS, direct full-line stores
// C[n][m'] = <q[:,n], k[:,m']>; writes energy fp32 + Ptil bf16 (exp, col-padded 0) + row psums
__global__ __launch_bounds__(256) void energy_k(const u16* __restrict__ qkT,
                                                float* __restrict__ outF,
                                                u16* __restrict__ P,
                                                float* __restrict__ psums) {
    __shared__ __align__(16) u16 S[16384];
    u16* As = S;
    u16* Bs = S + 8192;

    const int z = blockIdx.z;
    const size_t m0 = (size_t)blockIdx.y * 128;
    const size_t n0 = (size_t)blockIdx.x * 128;
    const u16* A = qkT + (size_t)z * NP * 128 + m0 * 128;        // q cols 0-63
    const u16* B = qkT + (size_t)z * NP * 128 + n0 * 128 + 64;   // k cols 64-127

    const int tid = threadIdx.x;
    const int lane = tid & 63, w = tid >> 6;
    const int wr = w >> 1, wc = w & 1;
    const int r32 = lane & 31, khalf = lane >> 5;

    // stage K=64 tile: linear LDS dest, pre-swizzled per-lane source (r8-proven pattern)
#pragma unroll
    for (int it = 0; it < 4; ++it) {
        int cb = (it * 4 + w) * 64;
        int chunk = cb + lane;
        int r = chunk >> 3;
        int kcb = ((chunk & 7) ^ (r & 7)) << 4;   // byte offset in 128B row
        gload16(A + (size_t)r * 128 + (kcb >> 1), &As[cb * 8]);
        gload16(B + (size_t)r * 128 + (kcb >> 1), &Bs[cb * 8]);
    }
    __syncthreads();

    f16v acc[2][2];
#pragma unroll
    for (int i = 0; i < 2; ++i)
#pragma unroll
        for (int j = 0; j < 2; ++j)
#pragma unroll
            for (int r = 0; r < 16; ++r) acc[i][j][r] = 0.f;

#pragma unroll
    for (int ks = 0; ks < 4; ++ks) {
        bfrag a0, a1, b0, b1;
        {
            int row = wr * 64 + r32;
            int L = row * 128 + ks * 32 + khalf * 16;
            a0 = *(const bfrag*)((const char*)As + (L ^ ((row & 7) << 4)));
            row += 32;
            L = row * 128 + ks * 32 + khalf * 16;
            a1 = *(const bfrag*)((const char*)As + (L ^ ((row & 7) << 4)));
        }
        {
            int row = wc * 64 + r32;
            int L = row * 128 + ks * 32 + khalf * 16;
            b0 = *(const bfrag*)((const char*)Bs + (L ^ ((row & 7) << 4)));
            row += 32;
            L = row * 128 + ks * 32 + khalf * 16;
            b1 = *(const bfrag*)((const char*)Bs + (L ^ ((row & 7) << 4)));
        }
        acc[0][0] = __builtin_amdgcn_mfma_f32_32x32x16_bf16(a0, b0, acc[0][0], 0, 0, 0);
        acc[0][1] = __builtin_amdgcn_mfma_f32_32x32x16_bf16(a0, b1, acc[0][1], 0, 0, 0);
        acc[1][0] = __builtin_amdgcn_mfma_f32_32x32x16_bf16(a1, b0, acc[1][0], 0, 0, 0);
        acc[1][1] = __builtin_amdgcn_mfma_f32_32x32x16_bf16(a1, b1, acc[1][1], 0, 0, 0);
    }

    // epilogue: direct stores. C layout: col=lane&31, row=(reg&3)+8*(reg>>2)+4*khalf.
    float* eb = outF + (size_t)z * ESZ;
    u16* Pb = P + (size_t)z * NP * NP;
    const bool interior = (m0 + 128 <= NN) && (n0 + 128 <= NN);
    float psl[2][16];
#pragma unroll
    for (int i = 0; i < 2; ++i)
#pragma unroll
        for (int r = 0; r < 16; ++r) psl[i][r] = 0.f;

#pragma unroll
    for (int i = 0; i < 2; ++i)
#pragma unroll
        for (int j = 0; j < 2; ++j)
#pragma unroll
            for (int reg = 0; reg < 16; ++reg) {
                int rowl = (reg & 3) + 8 * (reg >> 2) + 4 * khalf;
                size_t row = m0 + wr * 64 + i * 32 + rowl;
                size_t col = n0 + wc * 64 + j * 32 + r32;
                float v = acc[i][j][reg];
                float pe = (col < NN) ? __expf(v) : 0.f;
                if (interior || (row < NN && col < NN))
                    eb[row * NN + col] = v;                 // 32 lanes x 4B = full 128B line
                Pb[row * NP + col] = f2bf(pe);              // 64B chunk
                psl[i][reg] += pe;
            }

    // psums: reduce over 32 column-lanes (khalf groups stay separate: masks <= 16)
    float* pbase = psums + ((size_t)z * 68 + blockIdx.x * 2 + wc) * NP;
#pragma unroll
    for (int i = 0; i < 2; ++i)
#pragma unroll
        for (int reg = 0; reg < 16; ++reg) {
            float s = psl[i][reg];
            s += __shfl_xor(s, 1);
            s += __shfl_xor(s, 2);
            s += __shfl_xor(s, 4);
            s += __shfl_xor(s, 8);
            s += __shfl_xor(s, 16);
            if (r32 == 0) {
                int rowl = (reg & 3) + 8 * (reg >> 2) + 4 * khalf;
                pbase[m0 + wr * 64 + i * 32 + rowl] = s;
            }
        }
}

// ---------------- reduce partial sums -> invsum[b][n]
__global__ __launch_bounds__(256) void reduce_sums(const float* __restrict__ psums,
                                                   float* __restrict__ invsum) {
    int idx = blockIdx.x * 256 + threadIdx.x;
    if (idx >= BB * NP) return;
    int b = idx / NP, n = idx % NP;
    const float* p = psums + (size_t)b * 68 * NP + n;
    float s = 0.f;
#pragma unroll
    for (int ct = 0; ct < 68; ++ct) s += p[(size_t)ct * NP];
    invsum[idx] = 1.f / s;
}

// ---------------- PV GEMM (r6-proven): split-K x2, bijective XCD swizzle (c-fastest),
// 16x16 MFMA, bf16 ctx partials written coalesced via LDS repack.
__global__ __launch_bounds__(256) void gemm_pv(const u16* __restrict__ Vb,
                                               const u16* __restrict__ P,
                                               u16* __restrict__ ctxp,
                                               const float* __restrict__ invsum) {
    __shared__ __align__(16) u16 S[16384];
    u16* As = S;
    u16* Bs = S + 8192;

    unsigned flat = blockIdx.x + 34u * (blockIdx.y + 4u * blockIdx.z);
    unsigned swz = (flat & 7u) * 136u + (flat >> 3);
    unsigned zs = swz / 136u;
    unsigned rem = swz - zs * 136u;
    unsigned xs = rem >> 2;          // n-tile 0..33
    unsigned ys = rem & 3u;          // c-tile 0..3
    const int b = (int)(zs >> 1), half = (int)(zs & 1);

    const u16* A = Vb + (size_t)b * 512 * NP;
    const u16* Bm = P + (size_t)b * NP * NP;
    const size_t m0 = (size_t)ys * 128;
    const size_t n0 = (size_t)xs * 128;
    const u16* Ab = A + m0 * NP;
    const u16* Bb = Bm + n0 * NP;
    const int kbeg = half ? 2176 : 0;
    const int kend = half ? KPV : 2176;

    const int tid = threadIdx.x;
    const int lane = tid & 63, w = tid >> 6;
    const int wr = w >> 1, wc = w & 1;
    const int frow = lane & 15, fk = (lane >> 4) * 8;

    f4v acc[4][4];
#pragma unroll
    for (int i = 0; i < 4; ++i)
#pragma unroll
        for (int j = 0; j < 4; ++j) acc[i][j] = (f4v){0.f, 0.f, 0.f, 0.f};

    for (int kt = kbeg; kt < kend; kt += 64) {
        if (kt != kbeg) __syncthreads();
#pragma unroll
        for (int it = 0; it < 4; ++it) {
            int cb = (it * 4 + w) * 64;
            int chunk = cb + lane;
            int r = chunk >> 3;
            int kc = (chunk & 7) << 3;
            gload16(Ab + (size_t)r * NP + kt + kc, &As[cb * 8]);
            gload16(Bb + (size_t)r * NP + kt + kc, &Bs[cb * 8]);
        }
        __syncthreads();
#pragma unroll
        for (int ks = 0; ks < 2; ++ks) {
            bfrag af[4], bf[4];
#pragma unroll
            for (int i = 0; i < 4; ++i)
                af[i] = *(const bfrag*)&As[(wr * 64 + i * 16 + frow) * 64 + ks * 32 + fk];
#pragma unroll
            for (int j = 0; j < 4; ++j)
                bf[j] = *(const bfrag*)&Bs[(wc * 64 + j * 16 + frow) * 64 + ks * 32 + fk];
#pragma unroll
            for (int i = 0; i < 4; ++i)
#pragma unroll
                for (int j = 0; j < 4; ++j)
                    acc[i][j] = __builtin_amdgcn_mfma_f32_16x16x32_bf16(af[i], bf[j], acc[i][j], 0, 0, 0);
        }
    }

    const int rbase = (lane >> 4) * 4, cbase = lane & 15;
    const float* isb = invsum + (size_t)b * NP;
    __syncthreads();
#pragma unroll
    for (int j = 0; j < 4; ++j) {
        int cl = wc * 64 + j * 16 + cbase;
        float inv = isb[n0 + cl];
#pragma unroll
        for (int i = 0; i < 4; ++i) {
            int rl = wr * 64 + i * 16 + rbase;
#pragma unroll
            for (int r = 0; r < 4; ++r)
                S[(rl + r) * 128 + cl] = f2bf(acc[i][j][r] * inv);
        }
    }
    __syncthreads();
    u16* cb = ctxp + ((size_t)(half * BB + b) * 512 + m0) * NP + n0;
#pragma unroll
    for (int l = 0; l < 8; ++l) {
        int idx = tid + l * 256;
        int row = idx >> 4, c16 = idx & 15;
        *(int4*)(cb + (size_t)row * NP + c16 * 8) = *(const int4*)&S[row * 128 + c16 * 8];
    }
}

// ---------------- upsample: per-(b,c)-plane, ctx staged in LDS, bilinear 2x + residual
#define SLICE ((size_t)BB * 512 * NP)
__global__ __launch_bounds__(256) void upsample_add(const u16* __restrict__ ctxp,
                                                    const float* __restrict__ x,
                                                    const float* __restrict__ gm,
                                                    float* __restrict__ out) {
    __shared__ float cs[66 * 66];
    const int bc = blockIdx.x;                 // 0..2047 (b*512+c)
    const u16* p0 = ctxp + (size_t)bc * NP;
    const u16* p1 = p0 + SLICE;
    const int t = threadIdx.x;

    for (int idx = t; idx < 4225; idx += 256) {
        int r = idx / 65, c = idx - r * 65;
        cs[r * 66 + c] = bf2f(p0[idx]) + bf2f(p1[idx]);
    }
    if (t < 66) cs[t * 66 + 65] = 0.f;                 // weight-0 pads, keep finite
    if (t >= 128 && t < 193) cs[65 * 66 + (t - 128)] = 0.f;
    __syncthreads();

    const float g = gm[0];
    const float* xb = x + (size_t)bc * PLANE;
    float* ob = out + (size_t)bc * PLANE;
    for (int idx = t; idx < PLANE; idx += 256) {
        int yy = idx / 129, xx = idx - yy * 129;
        int i0 = yy >> 1, j0 = xx >> 1;
        float wy = 0.5f * (float)(yy & 1), wx = 0.5f * (float)(xx & 1);
        const float* c0 = &cs[i0 * 66 + j0];
        float c00 = c0[0], c01 = c0[1], c10 = c0[66], c11 = c0[67];
        float cx0 = c00 + wx * (c01 - c00);
        float cx1 = c10 + wx * (c11 - c10);
        ob[idx] = g * (cx0 + wy * (cx1 - cx0)) + xb[idx];
    }
}

// ---------------- workspace layout (bytes)
#define SZ_WC    ((size_t)640 * 512 * 2)
#define OFF_XST  (SZ_WC)
#define SZ_XST   ((size_t)BB * NP * 512 * 2)
#define OFF_QKT  (OFF_XST + SZ_XST)
#define SZ_QKT   ((size_t)BB * NP * 128 * 2)
#define OFF_V    (OFF_QKT + SZ_QKT)
#define SZ_V     ((size_t)BB * 512 * NP * 2)
#define OFF_PS   (OFF_V + SZ_V)
#define SZ_PS    ((size_t)BB * 68 * NP * 4)
#define OFF_INV  (OFF_PS + SZ_PS)
#define SZ_INV   ((size_t)BB * NP * 4)
#define OFF_CTXP (OFF_INV + SZ_INV)
#define SZ_CTXP  ((size_t)2 * BB * 512 * NP * 2)
#define OFF_P    (OFF_CTXP + SZ_CTXP)

extern "C" void kernel_launch(void* const* d_in, const int* in_sizes, int n_in,
                              void* d_out, int out_size, void* d_ws, size_t ws_size,
                              hipStream_t stream) {
    const float* x  = (const float*)d_in[0];
    const float* Wq = (const float*)d_in[1];
    const float* bq = (const float*)d_in[2];
    const float* Wk = (const float*)d_in[3];
    const float* bk = (const float*)d_in[4];
    const float* Wv = (const float*)d_in[5];
    const float* bv = (const float*)d_in[6];
    const float* gm = (const float*)d_in[7];

    float* out = (float*)d_out;
    float* energy = out + (size_t)OUTSZ;

    char* ws = (char*)d_ws;
    u16* Wc    = (u16*)(ws);
    u16* XsT   = (u16*)(ws + OFF_XST);
    u16* qkT   = (u16*)(ws + OFF_QKT);
    u16* V     = (u16*)(ws + OFF_V);
    float* psums  = (float*)(ws + OFF_PS);
    float* invsum = (float*)(ws + OFF_INV);
    u16* ctxp  = (u16*)(ws + OFF_CTXP);
    u16* P     = (u16*)(ws + OFF_P);

    setup_k<<<3456, 256, 0, stream>>>(Wq, Wk, Wv, x, Wc, XsT);
    gemm_qkv<<<680, 256, 0, stream>>>(Wc, XsT, qkT, V, bq, bk, bv);
    energy_k<<<dim3(34, 34, BB), 256, 0, stream>>>(qkT, energy, P, psums);
    reduce_sums<<<68, 256, 0, stream>>>(psums, invsum);
    gemm_pv<<<dim3(34, 4, 8), 256, 0, stream>>>(V, P, ctxp, invsum);
    upsample_add<<<2048, 256, 0, stream>>>(ctxp, x, gm, out);
}

// Round 10
// 436.041 us; speedup vs baseline: 1.0260x; 1.0260x over previous
//
#include <hip/hip_runtime.h>
#include <hip/hip_bf16.h>
#include <cstdint>

// Problem constants
#define BB 4
#define CC 512
#define CQK 64
#define HH 129
#define WW 129
#define HS 65
#define WSZ 65
#define NN 4225            // HS*WSZ
#define NP 4352            // padded N (34*128)
#define KPV 4288           // 67 K-tiles of 64; P cols 4288.. are zero
#define OUTSZ 34080768     // BB*CC*HH*WW
#define ESZ 17850625       // NN*NN
#define PLANE 16641        // 129*129

typedef unsigned short u16;
typedef __attribute__((ext_vector_type(8))) __bf16 bfrag;
typedef __attribute__((ext_vector_type(4))) float f4v;

__device__ inline u16 f2bf(float f) {
    union { float f; unsigned int u; } v; v.f = f;
    unsigned int u = v.u;
    return (u16)((u + 0x7FFFu + ((u >> 16) & 1u)) >> 16);
}
__device__ inline float bf2f(u16 v) {
    union { unsigned u; float f; } x; x.u = (unsigned)v << 16; return x.f;
}

// async global->LDS, 16 bytes per lane; lds dest must be wave-uniform base
__device__ __forceinline__ void gload16(const u16* g, u16* l) {
    __builtin_amdgcn_global_load_lds(
        (const __attribute__((address_space(1))) void*)g,
        (__attribute__((address_space(3))) void*)l, 16, 0, 0);
}

// ---------------- K0: merged setup — cast weights (blocks 0..1279) + subsample-T (rest)
__global__ __launch_bounds__(256) void setup_k(const float* __restrict__ Wq,
                                               const float* __restrict__ Wk,
                                               const float* __restrict__ Wv,
                                               const float* __restrict__ x,
                                               u16* __restrict__ Wc,
                                               u16* __restrict__ XsT) {
    __shared__ u16 tile[64][65];
    if (blockIdx.x < 1280) {
        int idx = blockIdx.x * 256 + threadIdx.x;
        int o = idx >> 9, c = idx & 511;
        float v = (o < 64) ? Wq[o * 512 + c] : (o < 128) ? Wk[(o - 64) * 512 + c] : Wv[(o - 128) * 512 + c];
        Wc[idx] = f2bf(v);
        return;
    }
    int bid = blockIdx.x - 1280;
    int nt = bid % 68;
    int ct = (bid / 68) & 7;
    int b = bid / 544;
    int t = threadIdx.x;
#pragma unroll
    for (int l = 0; l < 16; ++l) {
        int e = t + l * 256;
        int ci = e >> 6, nj = e & 63;
        int n = nt * 64 + nj;
        int nc = n < (NN - 1) ? n : (NN - 1);
        int i = nc / 65, j = nc % 65;
        int c = ct * 64 + ci;
        float v = x[(((size_t)b * CC + c) * HH + 2 * i) * WW + 2 * j];
        tile[ci][nj] = f2bf(v);
    }
    __syncthreads();
#pragma unroll
    for (int l = 0; l < 16; ++l) {
        int e = t + l * 256;
        int nj = e >> 6, ci = e & 63;
        XsT[((size_t)b * NP + nt * 64 + nj) * 512 + ct * 64 + ci] = tile[ci][nj];
    }
}

// ---------------- NT GEMM (m97 structure) for QKV and energy
// MODE 0: QKV  A=Wc[640][512], B=XsT[b], out -> qkT[n][o] (o<128) / V[o-128][n], +bias, bf16
//         flat grid 680 = 8 XCD slices x (17 n x 5 m, m fastest for B-panel L2 reuse)
// MODE 1: energy A=qkT[b] cols0-63 (q), B=qkT[b] cols64-127 (k), K=64,
//         out -> energy fp32 + Ptil bf16 (exp, col-padded 0, LDS-repacked) + row psums
template <int MODE>
__global__ __launch_bounds__(256) void gemm_nt(const u16* __restrict__ Abase,
                                               const u16* __restrict__ Bbase,
                                               int K, int lda, int ldb,
                                               float* __restrict__ outF,
                                               u16* __restrict__ out1, u16* __restrict__ out2,
                                               const float* __restrict__ bq,
                                               const float* __restrict__ bk,
                                               const float* __restrict__ bv,
                                               float* __restrict__ psums) {
    __shared__ __align__(16) u16 S[16384];   // As | Bs ; reused for repack
    u16* As = S;
    u16* Bs = S + 8192;

    int z; size_t m0, n0; unsigned xsave = 0;
    if (MODE == 0) {
        unsigned flat = blockIdx.x;
        unsigned s = flat & 7u;
        unsigned k = flat >> 3;
        unsigned m = k % 5u;
        unsigned nl = k / 5u;
        z = (int)(s >> 1);
        m0 = (size_t)m * 128;
        n0 = ((size_t)(s & 1u) * 17u + nl) * 128;
    } else {
        z = blockIdx.z;
        m0 = (size_t)blockIdx.y * 128;
        n0 = (size_t)blockIdx.x * 128;
        xsave = blockIdx.x;
    }

    const u16* A; const u16* Bm;
    if (MODE == 0) { A = Abase;                          Bm = Bbase + (size_t)z * NP * 512; }
    if (MODE == 1) { A = Abase + (size_t)z * NP * 128;   Bm = Bbase + (size_t)z * NP * 128 + 64; }

    const u16* Ab = A + m0 * lda;
    const u16* Bb = Bm + n0 * ldb;

    const int tid = threadIdx.x;
    const int lane = tid & 63, w = tid >> 6;
    const int wr = w >> 1, wc = w & 1;
    const int frow = lane & 15, fk = (lane >> 4) * 8;

    f4v acc[4][4];
#pragma unroll
    for (int i = 0; i < 4; ++i)
#pragma unroll
        for (int j = 0; j < 4; ++j) acc[i][j] = (f4v){0.f, 0.f, 0.f, 0.f};

    for (int kt = 0; kt < K; kt += 64) {
        if (kt) __syncthreads();
#pragma unroll
        for (int it = 0; it < 4; ++it) {
            int cb = (it * 4 + w) * 64;
            int chunk = cb + lane;
            int r = chunk >> 3;
            int kc = (chunk & 7) << 3;
            gload16(Ab + (size_t)r * lda + kt + kc, &As[cb * 8]);
            gload16(Bb + (size_t)r * ldb + kt + kc, &Bs[cb * 8]);
        }
        __syncthreads();
#pragma unroll
        for (int ks = 0; ks < 2; ++ks) {
            bfrag af[4], bf[4];
#pragma unroll
            for (int i = 0; i < 4; ++i)
                af[i] = *(const bfrag*)&As[(wr * 64 + i * 16 + frow) * 64 + ks * 32 + fk];
#pragma unroll
            for (int j = 0; j < 4; ++j)
                bf[j] = *(const bfrag*)&Bs[(wc * 64 + j * 16 + frow) * 64 + ks * 32 + fk];
#pragma unroll
            for (int i = 0; i < 4; ++i)
#pragma unroll
                for (int j = 0; j < 4; ++j)
                    acc[i][j] = __builtin_amdgcn_mfma_f32_16x16x32_bf16(af[i], bf[j], acc[i][j], 0, 0, 0);
        }
    }

    const int rbase = (lane >> 4) * 4, cbase = lane & 15;

    if (MODE == 0) {
        u16* out1b = out1 + (size_t)z * NP * 128;
        u16* out2b = out2 + (size_t)z * 512 * NP;
#pragma unroll
        for (int i = 0; i < 4; ++i)
#pragma unroll
            for (int j = 0; j < 4; ++j) {
                size_t row0 = m0 + wr * 64 + i * 16 + rbase;
                size_t col = n0 + wc * 64 + j * 16 + cbase;
#pragma unroll
                for (int r = 0; r < 4; ++r) {
                    int o = (int)(row0 + r);
                    float bias = (o < 64) ? bq[o] : (o < 128) ? bk[o - 64] : bv[o - 128];
                    u16 bb = f2bf(acc[i][j][r] + bias);
                    if (o < 128) out1b[col * 128 + o] = bb;
                    else out2b[(size_t)(o - 128) * NP + col] = bb;
                }
            }
    } else {
        float* eb = outF + (size_t)z * ESZ;
        u16* Pb = out1 + (size_t)z * NP * NP;
        float psl[4][4];
#pragma unroll
        for (int i = 0; i < 4; ++i)
#pragma unroll
            for (int r = 0; r < 4; ++r) psl[i][r] = 0.f;

        __syncthreads();   // all waves done reading As/Bs; S free for repack
#pragma unroll
        for (int i = 0; i < 4; ++i)
#pragma unroll
            for (int j = 0; j < 4; ++j) {
                int rl = wr * 64 + i * 16 + rbase;
                int cl = wc * 64 + j * 16 + cbase;
                size_t row0 = m0 + rl;
                size_t col = n0 + cl;
#pragma unroll
                for (int r = 0; r < 4; ++r) {
                    float v = acc[i][j][r];
                    size_t ro = row0 + r;
                    float pe = (col < NN) ? __expf(v) : 0.f;
                    if (ro < NN && col < NN) eb[ro * NN + col] = v;
                    S[(rl + r) * 128 + cl] = f2bf(pe);
                    psl[i][r] += pe;
                }
            }
        float* pbase = psums + ((size_t)z * 68 + xsave * 2 + wc) * NP;
#pragma unroll
        for (int i = 0; i < 4; ++i)
#pragma unroll
            for (int r = 0; r < 4; ++r) {
                float s = psl[i][r];
                s += __shfl_xor(s, 1);
                s += __shfl_xor(s, 2);
                s += __shfl_xor(s, 4);
                s += __shfl_xor(s, 8);
                if (cbase == 0)
                    pbase[m0 + wr * 64 + i * 16 + rbase + r] = s;
            }
        __syncthreads();
        u16* pb = Pb + m0 * NP + n0;
#pragma unroll
        for (int l = 0; l < 8; ++l) {
            int idx = tid + l * 256;
            int row = idx >> 4, c16 = idx & 15;
            *(int4*)(pb + (size_t)row * NP + c16 * 8) = *(const int4*)&S[row * 128 + c16 * 8];
        }
    }
}

// ---------------- reduce partial sums -> invsum[b][n]
__global__ __launch_bounds__(256) void reduce_sums(const float* __restrict__ psums,
                                                   float* __restrict__ invsum) {
    int idx = blockIdx.x * 256 + threadIdx.x;
    if (idx >= BB * NP) return;
    int b = idx / NP, n = idx % NP;
    const float* p = psums + (size_t)b * 68 * NP + n;
    float s = 0.f;
#pragma unroll
    for (int ct = 0; ct < 68; ++ct) s += p[(size_t)ct * NP];
    invsum[idx] = 1.f / s;
}

// ---------------- PV GEMM: FULL-K (no split), bijective XCD swizzle (c-fastest),
// 16x16 MFMA, bf16 ctx written coalesced via LDS repack.
// grid 544 = 8 XCDs x 68; slice order: (b, n-tile, c-tile fastest)
__global__ __launch_bounds__(256) void gemm_pv(const u16* __restrict__ Vb,
                                               const u16* __restrict__ P,
                                               u16* __restrict__ ctxp,
                                               const float* __restrict__ invsum) {
    __shared__ __align__(16) u16 S[16384];
    u16* As = S;
    u16* Bs = S + 8192;

    unsigned flat = blockIdx.x;
    unsigned swz = (flat & 7u) * 68u + (flat >> 3);   // 544 = 8*68, bijective
    unsigned b = swz / 136u;
    unsigned rem = swz - b * 136u;
    unsigned xs = rem >> 2;          // n-tile 0..33
    unsigned ys = rem & 3u;          // c-tile 0..3

    const u16* A = Vb + (size_t)b * 512 * NP;
    const u16* Bm = P + (size_t)b * NP * NP;
    const size_t m0 = (size_t)ys * 128;
    const size_t n0 = (size_t)xs * 128;
    const u16* Ab = A + m0 * NP;
    const u16* Bb = Bm + n0 * NP;

    const int tid = threadIdx.x;
    const int lane = tid & 63, w = tid >> 6;
    const int wr = w >> 1, wc = w & 1;
    const int frow = lane & 15, fk = (lane >> 4) * 8;

    f4v acc[4][4];
#pragma unroll
    for (int i = 0; i < 4; ++i)
#pragma unroll
        for (int j = 0; j < 4; ++j) acc[i][j] = (f4v){0.f, 0.f, 0.f, 0.f};

    for (int kt = 0; kt < KPV; kt += 64) {
        if (kt) __syncthreads();
#pragma unroll
        for (int it = 0; it < 4; ++it) {
            int cb = (it * 4 + w) * 64;
            int chunk = cb + lane;
            int r = chunk >> 3;
            int kc = (chunk & 7) << 3;
            gload16(Ab + (size_t)r * NP + kt + kc, &As[cb * 8]);
            gload16(Bb + (size_t)r * NP + kt + kc, &Bs[cb * 8]);
        }
        __syncthreads();
#pragma unroll
        for (int ks = 0; ks < 2; ++ks) {
            bfrag af[4], bf[4];
#pragma unroll
            for (int i = 0; i < 4; ++i)
                af[i] = *(const bfrag*)&As[(wr * 64 + i * 16 + frow) * 64 + ks * 32 + fk];
#pragma unroll
            for (int j = 0; j < 4; ++j)
                bf[j] = *(const bfrag*)&Bs[(wc * 64 + j * 16 + frow) * 64 + ks * 32 + fk];
#pragma unroll
            for (int i = 0; i < 4; ++i)
#pragma unroll
                for (int j = 0; j < 4; ++j)
                    acc[i][j] = __builtin_amdgcn_mfma_f32_16x16x32_bf16(af[i], bf[j], acc[i][j], 0, 0, 0);
        }
    }

    const int rbase = (lane >> 4) * 4, cbase = lane & 15;
    const float* isb = invsum + (size_t)b * NP;
    __syncthreads();
#pragma unroll
    for (int j = 0; j < 4; ++j) {
        int cl = wc * 64 + j * 16 + cbase;
        float inv = isb[n0 + cl];
#pragma unroll
        for (int i = 0; i < 4; ++i) {
            int rl = wr * 64 + i * 16 + rbase;
#pragma unroll
            for (int r = 0; r < 4; ++r)
                S[(rl + r) * 128 + cl] = f2bf(acc[i][j][r] * inv);
        }
    }
    __syncthreads();
    u16* cb = ctxp + ((size_t)b * 512 + m0) * NP + n0;
#pragma unroll
    for (int l = 0; l < 8; ++l) {
        int idx = tid + l * 256;
        int row = idx >> 4, c16 = idx & 15;
        *(int4*)(cb + (size_t)row * NP + c16 * 8) = *(const int4*)&S[row * 128 + c16 * 8];
    }
}

// ---------------- upsample: per-(b,c)-plane, ctx staged in LDS, bilinear 2x + residual
__global__ __launch_bounds__(256) void upsample_add(const u16* __restrict__ ctxp,
                                                    const float* __restrict__ x,
                                                    const float* __restrict__ gm,
                                                    float* __restrict__ out) {
    __shared__ float cs[66 * 66];
    const int bc = blockIdx.x;                 // 0..2047 (b*512+c)
    const u16* p0 = ctxp + (size_t)bc * NP;
    const int t = threadIdx.x;

    for (int idx = t; idx < 4225; idx += 256) {
        int r = idx / 65, c = idx - r * 65;
        cs[r * 66 + c] = bf2f(p0[idx]);
    }
    if (t < 66) cs[t * 66 + 65] = 0.f;                 // weight-0 pads, keep finite
    if (t >= 128 && t < 193) cs[65 * 66 + (t - 128)] = 0.f;
    __syncthreads();

    const float g = gm[0];
    const float* xb = x + (size_t)bc * PLANE;
    float* ob = out + (size_t)bc * PLANE;
    for (int idx = t; idx < PLANE; idx += 256) {
        int yy = idx / 129, xx = idx - yy * 129;
        int i0 = yy >> 1, j0 = xx >> 1;
        float wy = 0.5f * (float)(yy & 1), wx = 0.5f * (float)(xx & 1);
        const float* c0 = &cs[i0 * 66 + j0];
        float c00 = c0[0], c01 = c0[1], c10 = c0[66], c11 = c0[67];
        float cx0 = c00 + wx * (c01 - c00);
        float cx1 = c10 + wx * (c11 - c10);
        ob[idx] = g * (cx0 + wy * (cx1 - cx0)) + xb[idx];
    }
}

// ---------------- workspace layout (bytes)
#define SZ_WC    ((size_t)640 * 512 * 2)
#define OFF_XST  (SZ_WC)
#define SZ_XST   ((size_t)BB * NP * 512 * 2)
#define OFF_QKT  (OFF_XST + SZ_XST)
#define SZ_QKT   ((size_t)BB * NP * 128 * 2)
#define OFF_V    (OFF_QKT + SZ_QKT)
#define SZ_V     ((size_t)BB * 512 * NP * 2)
#define OFF_PS   (OFF_V + SZ_V)
#define SZ_PS    ((size_t)BB * 68 * NP * 4)
#define OFF_INV  (OFF_PS + SZ_PS)
#define SZ_INV   ((size_t)BB * NP * 4)
#define OFF_CTXP (OFF_INV + SZ_INV)
#define SZ_CTXP  ((size_t)BB * 512 * NP * 2)
#define OFF_P    (OFF_CTXP + SZ_CTXP)

extern "C" void kernel_launch(void* const* d_in, const int* in_sizes, int n_in,
                              void* d_out, int out_size, void* d_ws, size_t ws_size,
                              hipStream_t stream) {
    const float* x  = (const float*)d_in[0];
    const float* Wq = (const float*)d_in[1];
    const float* bq = (const float*)d_in[2];
    const float* Wk = (const float*)d_in[3];
    const float* bk = (const float*)d_in[4];
    const float* Wv = (const float*)d_in[5];
    const float* bv = (const float*)d_in[6];
    const float* gm = (const float*)d_in[7];

    float* out = (float*)d_out;
    float* energy = out + (size_t)OUTSZ;

    char* ws = (char*)d_ws;
    u16* Wc    = (u16*)(ws);
    u16* XsT   = (u16*)(ws + OFF_XST);
    u16* qkT   = (u16*)(ws + OFF_QKT);
    u16* V     = (u16*)(ws + OFF_V);
    float* psums  = (float*)(ws + OFF_PS);
    float* invsum = (float*)(ws + OFF_INV);
    u16* ctxp  = (u16*)(ws + OFF_CTXP);
    u16* P     = (u16*)(ws + OFF_P);

    setup_k<<<3456, 256, 0, stream>>>(Wq, Wk, Wv, x, Wc, XsT);
    gemm_nt<0><<<680, 256, 0, stream>>>(Wc, XsT, 512, 512, 512,
                                        nullptr, qkT, V, bq, bk, bv, nullptr);
    gemm_nt<1><<<dim3(34, 34, BB), 256, 0, stream>>>(qkT, qkT, 64, 128, 128,
                                                     energy, P, nullptr, nullptr, nullptr, nullptr,
                                                     psums);
    reduce_sums<<<68, 256, 0, stream>>>(psums, invsum);
    gemm_pv<<<544, 256, 0, stream>>>(V, P, ctxp, invsum);
    upsample_add<<<2048, 256, 0, stream>>>(ctxp, x, gm, out);
}

// Round 11
// 419.371 us; speedup vs baseline: 1.0668x; 1.0398x over previous
//
#include <hip/hip_runtime.h>
#include <hip/hip_bf16.h>
#include <cstdint>

// Problem constants
#define BB 4
#define CC 512
#define CQK 64
#define HH 129
#define WW 129
#define HS 65
#define WSZ 65
#define NN 4225            // HS*WSZ
#define NP 4352            // padded N (34*128)
#define KPV 4288           // 67 K-tiles of 64; P cols 4288.. are zero
#define OUTSZ 34080768     // BB*CC*HH*WW
#define ESZ 17850625       // NN*NN
#define PLANE 16641        // 129*129

typedef unsigned short u16;
typedef __attribute__((ext_vector_type(8))) __bf16 bfrag;
typedef __attribute__((ext_vector_type(4))) float f4v;

__device__ inline u16 f2bf(float f) {
    union { float f; unsigned int u; } v; v.f = f;
    unsigned int u = v.u;
    return (u16)((u + 0x7FFFu + ((u >> 16) & 1u)) >> 16);
}
__device__ inline float bf2f(u16 v) {
    union { unsigned u; float f; } x; x.u = (unsigned)v << 16; return x.f;
}

// async global->LDS, 16 bytes per lane; lds dest must be wave-uniform base
__device__ __forceinline__ void gload16(const u16* g, u16* l) {
    __builtin_amdgcn_global_load_lds(
        (const __attribute__((address_space(1))) void*)g,
        (__attribute__((address_space(3))) void*)l, 16, 0, 0);
}

// ---------------- K0: merged setup — cast weights (blocks 0..1279) + subsample-T (rest)
__global__ __launch_bounds__(256) void setup_k(const float* __restrict__ Wq,
                                               const float* __restrict__ Wk,
                                               const float* __restrict__ Wv,
                                               const float* __restrict__ x,
                                               u16* __restrict__ Wc,
                                               u16* __restrict__ XsT) {
    __shared__ u16 tile[64][65];
    if (blockIdx.x < 1280) {
        int idx = blockIdx.x * 256 + threadIdx.x;
        int o = idx >> 9, c = idx & 511;
        float v = (o < 64) ? Wq[o * 512 + c] : (o < 128) ? Wk[(o - 64) * 512 + c] : Wv[(o - 128) * 512 + c];
        Wc[idx] = f2bf(v);
        return;
    }
    int bid = blockIdx.x - 1280;
    int nt = bid % 68;
    int ct = (bid / 68) & 7;
    int b = bid / 544;
    int t = threadIdx.x;
#pragma unroll
    for (int l = 0; l < 16; ++l) {
        int e = t + l * 256;
        int ci = e >> 6, nj = e & 63;
        int n = nt * 64 + nj;
        int nc = n < (NN - 1) ? n : (NN - 1);
        int i = nc / 65, j = nc % 65;
        int c = ct * 64 + ci;
        float v = x[(((size_t)b * CC + c) * HH + 2 * i) * WW + 2 * j];
        tile[ci][nj] = f2bf(v);
    }
    __syncthreads();
#pragma unroll
    for (int l = 0; l < 16; ++l) {
        int e = t + l * 256;
        int nj = e >> 6, ci = e & 63;
        XsT[((size_t)b * NP + nt * 64 + nj) * 512 + ct * 64 + ci] = tile[ci][nj];
    }
}

// ---------------- NT GEMM (m97 structure) for QKV and energy
// MODE 0: QKV  A=Wc[640][512], B=XsT[b], out -> qkT[n][o] (o<128) / V[o-128][n], +bias, bf16
//         flat grid 680 = 8 XCD slices x (17 n x 5 m, m fastest for B-panel L2 reuse)
// MODE 1: energy A=qkT[b] cols0-63 (q), B=qkT[b] cols64-127 (k), K=64,
//         out -> energy fp32 + Ptil bf16 (exp, col-padded 0, LDS-repacked) + row psums
template <int MODE>
__global__ __launch_bounds__(256) void gemm_nt(const u16* __restrict__ Abase,
                                               const u16* __restrict__ Bbase,
                                               int K, int lda, int ldb,
                                               float* __restrict__ outF,
                                               u16* __restrict__ out1, u16* __restrict__ out2,
                                               const float* __restrict__ bq,
                                               const float* __restrict__ bk,
                                               const float* __restrict__ bv,
                                               float* __restrict__ psums) {
    __shared__ __align__(16) u16 S[16384];   // As | Bs ; reused for repack
    u16* As = S;
    u16* Bs = S + 8192;

    int z; size_t m0, n0; unsigned xsave = 0;
    if (MODE == 0) {
        unsigned flat = blockIdx.x;
        unsigned s = flat & 7u;
        unsigned k = flat >> 3;
        unsigned m = k % 5u;
        unsigned nl = k / 5u;
        z = (int)(s >> 1);
        m0 = (size_t)m * 128;
        n0 = ((size_t)(s & 1u) * 17u + nl) * 128;
    } else {
        z = blockIdx.z;
        m0 = (size_t)blockIdx.y * 128;
        n0 = (size_t)blockIdx.x * 128;
        xsave = blockIdx.x;
    }

    const u16* A; const u16* Bm;
    if (MODE == 0) { A = Abase;                          Bm = Bbase + (size_t)z * NP * 512; }
    if (MODE == 1) { A = Abase + (size_t)z * NP * 128;   Bm = Bbase + (size_t)z * NP * 128 + 64; }

    const u16* Ab = A + m0 * lda;
    const u16* Bb = Bm + n0 * ldb;

    const int tid = threadIdx.x;
    const int lane = tid & 63, w = tid >> 6;
    const int wr = w >> 1, wc = w & 1;
    const int frow = lane & 15, fk = (lane >> 4) * 8;

    f4v acc[4][4];
#pragma unroll
    for (int i = 0; i < 4; ++i)
#pragma unroll
        for (int j = 0; j < 4; ++j) acc[i][j] = (f4v){0.f, 0.f, 0.f, 0.f};

    for (int kt = 0; kt < K; kt += 64) {
        if (kt) __syncthreads();
#pragma unroll
        for (int it = 0; it < 4; ++it) {
            int cb = (it * 4 + w) * 64;
            int chunk = cb + lane;
            int r = chunk >> 3;
            int kc = (chunk & 7) << 3;
            gload16(Ab + (size_t)r * lda + kt + kc, &As[cb * 8]);
            gload16(Bb + (size_t)r * ldb + kt + kc, &Bs[cb * 8]);
        }
        __syncthreads();
#pragma unroll
        for (int ks = 0; ks < 2; ++ks) {
            bfrag af[4], bf[4];
#pragma unroll
            for (int i = 0; i < 4; ++i)
                af[i] = *(const bfrag*)&As[(wr * 64 + i * 16 + frow) * 64 + ks * 32 + fk];
#pragma unroll
            for (int j = 0; j < 4; ++j)
                bf[j] = *(const bfrag*)&Bs[(wc * 64 + j * 16 + frow) * 64 + ks * 32 + fk];
#pragma unroll
            for (int i = 0; i < 4; ++i)
#pragma unroll
                for (int j = 0; j < 4; ++j)
                    acc[i][j] = __builtin_amdgcn_mfma_f32_16x16x32_bf16(af[i], bf[j], acc[i][j], 0, 0, 0);
        }
    }

    const int rbase = (lane >> 4) * 4, cbase = lane & 15;

    if (MODE == 0) {
        u16* out1b = out1 + (size_t)z * NP * 128;
        u16* out2b = out2 + (size_t)z * 512 * NP;
#pragma unroll
        for (int i = 0; i < 4; ++i)
#pragma unroll
            for (int j = 0; j < 4; ++j) {
                size_t row0 = m0 + wr * 64 + i * 16 + rbase;
                size_t col = n0 + wc * 64 + j * 16 + cbase;
#pragma unroll
                for (int r = 0; r < 4; ++r) {
                    int o = (int)(row0 + r);
                    float bias = (o < 64) ? bq[o] : (o < 128) ? bk[o - 64] : bv[o - 128];
                    u16 bb = f2bf(acc[i][j][r] + bias);
                    if (o < 128) out1b[col * 128 + o] = bb;
                    else out2b[(size_t)(o - 128) * NP + col] = bb;
                }
            }
    } else {
        float* eb = outF + (size_t)z * ESZ;
        u16* Pb = out1 + (size_t)z * NP * NP;
        float psl[4][4];
#pragma unroll
        for (int i = 0; i < 4; ++i)
#pragma unroll
            for (int r = 0; r < 4; ++r) psl[i][r] = 0.f;

        __syncthreads();   // all waves done reading As/Bs; S free for repack
#pragma unroll
        for (int i = 0; i < 4; ++i)
#pragma unroll
            for (int j = 0; j < 4; ++j) {
                int rl = wr * 64 + i * 16 + rbase;
                int cl = wc * 64 + j * 16 + cbase;
                size_t row0 = m0 + rl;
                size_t col = n0 + cl;
#pragma unroll
                for (int r = 0; r < 4; ++r) {
                    float v = acc[i][j][r];
                    size_t ro = row0 + r;
                    float pe = (col < NN) ? __expf(v) : 0.f;
                    if (ro < NN && col < NN) eb[ro * NN + col] = v;
                    S[(rl + r) * 128 + cl] = f2bf(pe);
                    psl[i][r] += pe;
                }
            }
        float* pbase = psums + ((size_t)z * 68 + xsave * 2 + wc) * NP;
#pragma unroll
        for (int i = 0; i < 4; ++i)
#pragma unroll
            for (int r = 0; r < 4; ++r) {
                float s = psl[i][r];
                s += __shfl_xor(s, 1);
                s += __shfl_xor(s, 2);
                s += __shfl_xor(s, 4);
                s += __shfl_xor(s, 8);
                if (cbase == 0)
                    pbase[m0 + wr * 64 + i * 16 + rbase + r] = s;
            }
        __syncthreads();
        u16* pb = Pb + m0 * NP + n0;
#pragma unroll
        for (int l = 0; l < 8; ++l) {
            int idx = tid + l * 256;
            int row = idx >> 4, c16 = idx & 15;
            *(int4*)(pb + (size_t)row * NP + c16 * 8) = *(const int4*)&S[row * 128 + c16 * 8];
        }
    }
}

// ---------------- reduce partial sums -> invsum[b][n]
__global__ __launch_bounds__(256) void reduce_sums(const float* __restrict__ psums,
                                                   float* __restrict__ invsum) {
    int idx = blockIdx.x * 256 + threadIdx.x;
    if (idx >= BB * NP) return;
    int b = idx / NP, n = idx % NP;
    const float* p = psums + (size_t)b * 68 * NP + n;
    float s = 0.f;
#pragma unroll
    for (int ct = 0; ct < 68; ++ct) s += p[(size_t)ct * NP];
    invsum[idx] = 1.f / s;
}

// ---------------- PV GEMM: split-K x2, bijective XCD swizzle (c-fastest in slice),
// bf16 ctx partials written coalesced via LDS repack.
__global__ __launch_bounds__(256) void gemm_pv(const u16* __restrict__ Vb,
                                               const u16* __restrict__ P,
                                               u16* __restrict__ ctxp,
                                               const float* __restrict__ invsum) {
    __shared__ __align__(16) u16 S[16384];
    u16* As = S;
    u16* Bs = S + 8192;

    unsigned flat = blockIdx.x + 34u * (blockIdx.y + 4u * blockIdx.z);
    unsigned swz = (flat & 7u) * 136u + (flat >> 3);
    unsigned zs = swz / 136u;
    unsigned rem = swz - zs * 136u;
    unsigned xs = rem >> 2;          // n-tile 0..33
    unsigned ys = rem & 3u;          // c-tile 0..3
    const int b = (int)(zs >> 1), half = (int)(zs & 1);

    const u16* A = Vb + (size_t)b * 512 * NP;
    const u16* Bm = P + (size_t)b * NP * NP;
    const size_t m0 = (size_t)ys * 128;
    const size_t n0 = (size_t)xs * 128;
    const u16* Ab = A + m0 * NP;
    const u16* Bb = Bm + n0 * NP;
    const int kbeg = half ? 2176 : 0;
    const int kend = half ? KPV : 2176;

    const int tid = threadIdx.x;
    const int lane = tid & 63, w = tid >> 6;
    const int wr = w >> 1, wc = w & 1;
    const int frow = lane & 15, fk = (lane >> 4) * 8;

    f4v acc[4][4];
#pragma unroll
    for (int i = 0; i < 4; ++i)
#pragma unroll
        for (int j = 0; j < 4; ++j) acc[i][j] = (f4v){0.f, 0.f, 0.f, 0.f};

    for (int kt = kbeg; kt < kend; kt += 64) {
        if (kt != kbeg) __syncthreads();
#pragma unroll
        for (int it = 0; it < 4; ++it) {
            int cb = (it * 4 + w) * 64;
            int chunk = cb + lane;
            int r = chunk >> 3;
            int kc = (chunk & 7) << 3;
            gload16(Ab + (size_t)r * NP + kt + kc, &As[cb * 8]);
            gload16(Bb + (size_t)r * NP + kt + kc, &Bs[cb * 8]);
        }
        __syncthreads();
#pragma unroll
        for (int ks = 0; ks < 2; ++ks) {
            bfrag af[4], bf[4];
#pragma unroll
            for (int i = 0; i < 4; ++i)
                af[i] = *(const bfrag*)&As[(wr * 64 + i * 16 + frow) * 64 + ks * 32 + fk];
#pragma unroll
            for (int j = 0; j < 4; ++j)
                bf[j] = *(const bfrag*)&Bs[(wc * 64 + j * 16 + frow) * 64 + ks * 32 + fk];
#pragma unroll
            for (int i = 0; i < 4; ++i)
#pragma unroll
                for (int j = 0; j < 4; ++j)
                    acc[i][j] = __builtin_amdgcn_mfma_f32_16x16x32_bf16(af[i], bf[j], acc[i][j], 0, 0, 0);
        }
    }

    const int rbase = (lane >> 4) * 4, cbase = lane & 15;
    const float* isb = invsum + (size_t)b * NP;
    __syncthreads();
#pragma unroll
    for (int j = 0; j < 4; ++j) {
        int cl = wc * 64 + j * 16 + cbase;
        float inv = isb[n0 + cl];
#pragma unroll
        for (int i = 0; i < 4; ++i) {
            int rl = wr * 64 + i * 16 + rbase;
#pragma unroll
            for (int r = 0; r < 4; ++r)
                S[(rl + r) * 128 + cl] = f2bf(acc[i][j][r] * inv);
        }
    }
    __syncthreads();
    u16* cb = ctxp + ((size_t)(half * BB + b) * 512 + m0) * NP + n0;
#pragma unroll
    for (int l = 0; l < 8; ++l) {
        int idx = tid + l * 256;
        int row = idx >> 4, c16 = idx & 15;
        *(int4*)(cb + (size_t)row * NP + c16 * 8) = *(const int4*)&S[row * 128 + c16 * 8];
    }
}

// ---------------- upsample: per-(b,c)-plane, ctx staged in LDS, bilinear 2x + residual
#define SLICE ((size_t)BB * 512 * NP)
__global__ __launch_bounds__(256) void upsample_add(const u16* __restrict__ ctxp,
                                                    const float* __restrict__ x,
                                                    const float* __restrict__ gm,
                                                    float* __restrict__ out) {
    __shared__ float cs[66 * 66];
    const int bc = blockIdx.x;                 // 0..2047 (b*512+c)
    const u16* p0 = ctxp + (size_t)bc * NP;
    const u16* p1 = p0 + SLICE;
    const int t = threadIdx.x;

    for (int idx = t; idx < 4225; idx += 256) {
        int r = idx / 65, c = idx - r * 65;
        cs[r * 66 + c] = bf2f(p0[idx]) + bf2f(p1[idx]);
    }
    if (t < 66) cs[t * 66 + 65] = 0.f;                 // weight-0 pads, keep finite
    if (t >= 128 && t < 193) cs[65 * 66 + (t - 128)] = 0.f;
    __syncthreads();

    const float g = gm[0];
    const float* xb = x + (size_t)bc * PLANE;
    float* ob = out + (size_t)bc * PLANE;
    for (int idx = t; idx < PLANE; idx += 256) {
        int yy = idx / 129, xx = idx - yy * 129;
        int i0 = yy >> 1, j0 = xx >> 1;
        float wy = 0.5f * (float)(yy & 1), wx = 0.5f * (float)(xx & 1);
        const float* c0 = &cs[i0 * 66 + j0];
        float c00 = c0[0], c01 = c0[1], c10 = c0[66], c11 = c0[67];
        float cx0 = c00 + wx * (c01 - c00);
        float cx1 = c10 + wx * (c11 - c10);
        ob[idx] = g * (cx0 + wy * (cx1 - cx0)) + xb[idx];
    }
}

// ---------------- workspace layout (bytes)
#define SZ_WC    ((size_t)640 * 512 * 2)
#define OFF_XST  (SZ_WC)
#define SZ_XST   ((size_t)BB * NP * 512 * 2)
#define OFF_QKT  (OFF_XST + SZ_XST)
#define SZ_QKT   ((size_t)BB * NP * 128 * 2)
#define OFF_V    (OFF_QKT + SZ_QKT)
#define SZ_V     ((size_t)BB * 512 * NP * 2)
#define OFF_PS   (OFF_V + SZ_V)
#define SZ_PS    ((size_t)BB * 68 * NP * 4)
#define OFF_INV  (OFF_PS + SZ_PS)
#define SZ_INV   ((size_t)BB * NP * 4)
#define OFF_CTXP (OFF_INV + SZ_INV)
#define SZ_CTXP  ((size_t)2 * BB * 512 * NP * 2)
#define OFF_P    (OFF_CTXP + SZ_CTXP)

extern "C" void kernel_launch(void* const* d_in, const int* in_sizes, int n_in,
                              void* d_out, int out_size, void* d_ws, size_t ws_size,
                              hipStream_t stream) {
    const float* x  = (const float*)d_in[0];
    const float* Wq = (const float*)d_in[1];
    const float* bq = (const float*)d_in[2];
    const float* Wk = (const float*)d_in[3];
    const float* bk = (const float*)d_in[4];
    const float* Wv = (const float*)d_in[5];
    const float* bv = (const float*)d_in[6];
    const float* gm = (const float*)d_in[7];

    float* out = (float*)d_out;
    float* energy = out + (size_t)OUTSZ;

    char* ws = (char*)d_ws;
    u16* Wc    = (u16*)(ws);
    u16* XsT   = (u16*)(ws + OFF_XST);
    u16* qkT   = (u16*)(ws + OFF_QKT);
    u16* V     = (u16*)(ws + OFF_V);
    float* psums  = (float*)(ws + OFF_PS);
    float* invsum = (float*)(ws + OFF_INV);
    u16* ctxp  = (u16*)(ws + OFF_CTXP);
    u16* P     = (u16*)(ws + OFF_P);

    setup_k<<<3456, 256, 0, stream>>>(Wq, Wk, Wv, x, Wc, XsT);
    gemm_nt<0><<<680, 256, 0, stream>>>(Wc, XsT, 512, 512, 512,
                                        nullptr, qkT, V, bq, bk, bv, nullptr);
    gemm_nt<1><<<dim3(34, 34, BB), 256, 0, stream>>>(qkT, qkT, 64, 128, 128,
                                                     energy, P, nullptr, nullptr, nullptr, nullptr,
                                                     psums);
    reduce_sums<<<68, 256, 0, stream>>>(psums, invsum);
    gemm_pv<<<dim3(34, 4, 8), 256, 0, stream>>>(V, P, ctxp, invsum);
    upsample_add<<<2048, 256, 0, stream>>>(ctxp, x, gm, out);
}